// Round 17
// baseline (979.303 us; speedup 1.0000x reference)
//
#include <hip/hip_runtime.h>

#define PRE 2000
#define TOPN 1000

typedef __attribute__((ext_vector_type(8))) short short8t;
typedef __attribute__((ext_vector_type(4))) float f32x4;
typedef unsigned short ushort_t;

__device__ inline unsigned short bf16_rne(float x) {
    unsigned u = __float_as_uint(x);
    unsigned r = u + 0x7FFFu + ((u >> 16) & 1u);
    return (unsigned short)(r >> 16);
}

__device__ inline void split3_bf16(float x, unsigned short& h, unsigned short& m,
                                   unsigned short& l) {
    h = bf16_rne(x);
    float hf = __uint_as_float((unsigned)h << 16);
    float r1 = x - hf;
    m = bf16_rne(r1);
    float mf = __uint_as_float((unsigned)m << 16);
    l = bf16_rne(r1 - mf);
}

// ============================================================================
// k_fused: blocks 0..1 = greedy NMS v2 (start first, hide under GEMM);
// blocks 2..1569 = fc1 T-matrix GEMM (plain bf16, XCD swizzle, bf16 out).
// ============================================================================

__global__ __launch_bounds__(256, 4) void k_fused(
    const ushort_t* __restrict__ Aq, const ushort_t* __restrict__ Bq,
    ushort_t* __restrict__ T,
    const unsigned* __restrict__ mask, unsigned* __restrict__ keep)
{
    if (blockIdx.x < 2) {
        if (threadIdx.x >= 64) return;
        const int b = blockIdx.x;
        const int lane = threadIdx.x;
        unsigned kw = (lane < 62) ? 0xFFFFFFFFu : (lane == 62 ? 0xFFFFu : 0u);
        const unsigned* mbase = mask + (size_t)b * PRE * 63;
        bool ld = (lane < 63);

        unsigned buf[16];
#pragma unroll
        for (int d = 0; d < 16; d++)
            buf[d] = ld ? mbase[(size_t)d * 63 + lane] : 0u;

        for (int g = 0; g < PRE; g += 16) {
#pragma unroll
            for (int d = 0; d < 16; d++) {
                int i = g + d;
                unsigned row = buf[d];
                int ip = i + 16;
                buf[d] = (ld && ip < PRE) ? mbase[(size_t)ip * 63 + lane] : 0u;
                unsigned wv = (unsigned)__shfl((int)kw, i >> 5);
                if ((wv >> (i & 31)) & 1u)
                    kw &= ~row;
            }
        }
        if (lane < 63) keep[b * 63 + lane] = kw;
        return;
    }

    const int flat = blockIdx.x - 2;         // 0..1567
    const int xcd  = flat & 7;
    const int jj   = flat >> 3;
    const int wg   = xcd * 196 + jj;
    const int b    = wg / 784;
    const int rem  = wg - b * 784;
    const int nt   = rem >> 3;               // 0..97
    const int mt   = rem & 7;                // 0..7

    const int tid  = threadIdx.x;
    const int wid  = tid >> 6, lane = tid & 63;
    const int wm_g = (wid >> 1) * 4;
    const int wn_g = (wid & 1) * 4;

    f32x4 acc[4][4];
#pragma unroll
    for (int i = 0; i < 4; i++)
#pragma unroll
        for (int j = 0; j < 4; j++) acc[i][j] = (f32x4){0.f, 0.f, 0.f, 0.f};

    const size_t aoff = (size_t)b * 2097152 + (size_t)mt * 262144
                      + (size_t)wm_g * 512 + (size_t)lane * 8;
    const size_t boff = (size_t)nt * 262144 + (size_t)wn_g * 512 + (size_t)lane * 8;
    const ushort_t* pA = Aq + aoff;
    const ushort_t* pB = Bq + boff;

    for (int ks = 0; ks < 64; ks++) {
        const size_t so = (size_t)ks * 4096;
        short8t a[4], bb[4];
#pragma unroll
        for (int f = 0; f < 4; f++) {
            a[f]  = *(const short8t*)(pA + so + f * 512);
            bb[f] = *(const short8t*)(pB + so + f * 512);
        }
#pragma unroll
        for (int mf = 0; mf < 4; mf++)
#pragma unroll
            for (int nf = 0; nf < 4; nf++)
                acc[mf][nf] = __builtin_amdgcn_mfma_f32_16x16x32_bf16(
                    a[mf], bb[nf], acc[mf][nf], 0, 0, 0);
    }

    ushort_t* Tb = T + (size_t)b * 12845056;   // 1024*12544
    const int rbase = (lane >> 4) * 4;
    const int lrow  = lane & 15;
#pragma unroll
    for (int mf = 0; mf < 4; mf++) {
#pragma unroll
        for (int nf = 0; nf < 4; nf++) {
            int col = nt * 128 + (wn_g + nf) * 16 + lrow;
#pragma unroll
            for (int r = 0; r < 4; r++) {
                int row = mt * 128 + (wm_g + mf) * 16 + rbase + r;
                Tb[(size_t)row * 12544 + col] = bf16_rne(acc[mf][nf][r]);
            }
        }
    }
}

// ============================================================================
// k_gemm6: 3-way split (6 products ~ f32 accuracy) — rank-critical GEMMs.
// ============================================================================

__global__ __launch_bounds__(256, 2) void k_gemm6(
    const ushort_t* __restrict__ A0, const ushort_t* __restrict__ A1,
    const ushort_t* __restrict__ A2,
    const ushort_t* __restrict__ B0, const ushort_t* __restrict__ B1,
    const ushort_t* __restrict__ B2,
    float* __restrict__ C, int ks_per_z, int KS_TOT, int ldc)
{
    const int tid  = threadIdx.x;
    const int wid  = tid >> 6, lane = tid & 63;
    const int wm_g = (wid >> 1) * 4;
    const int wn_g = (wid & 1) * 4;
    const int mt   = blockIdx.x;
    const int nt   = blockIdx.y;
    const int z    = blockIdx.z;

    f32x4 acc[4][4];
#pragma unroll
    for (int i = 0; i < 4; i++)
#pragma unroll
        for (int j = 0; j < 4; j++) acc[i][j] = (f32x4){0.f, 0.f, 0.f, 0.f};

    const size_t aoff = (size_t)mt * KS_TOT * 4096 + (size_t)wm_g * 512 + (size_t)lane * 8;
    const size_t boff = (size_t)nt * KS_TOT * 4096 + (size_t)wn_g * 512 + (size_t)lane * 8;
    const ushort_t* pA0 = A0 + aoff;
    const ushort_t* pA1 = A1 + aoff;
    const ushort_t* pA2 = A2 + aoff;
    const ushort_t* pB0 = B0 + boff;
    const ushort_t* pB1 = B1 + boff;
    const ushort_t* pB2 = B2 + boff;

    const int ks0 = z * ks_per_z;
    for (int ks = ks0; ks < ks0 + ks_per_z; ks++) {
        const size_t so = (size_t)ks * 4096;
        short8t a0[4], a1[4], a2[4], b0[4], b1[4], b2[4];
#pragma unroll
        for (int f = 0; f < 4; f++) {
            a0[f] = *(const short8t*)(pA0 + so + f * 512);
            a1[f] = *(const short8t*)(pA1 + so + f * 512);
            a2[f] = *(const short8t*)(pA2 + so + f * 512);
            b0[f] = *(const short8t*)(pB0 + so + f * 512);
            b1[f] = *(const short8t*)(pB1 + so + f * 512);
            b2[f] = *(const short8t*)(pB2 + so + f * 512);
        }
#pragma unroll
        for (int mf = 0; mf < 4; mf++)
#pragma unroll
            for (int nf = 0; nf < 4; nf++) {
                f32x4 c = acc[mf][nf];
                c = __builtin_amdgcn_mfma_f32_16x16x32_bf16(a0[mf], b0[nf], c, 0, 0, 0);
                c = __builtin_amdgcn_mfma_f32_16x16x32_bf16(a0[mf], b1[nf], c, 0, 0, 0);
                c = __builtin_amdgcn_mfma_f32_16x16x32_bf16(a1[mf], b0[nf], c, 0, 0, 0);
                c = __builtin_amdgcn_mfma_f32_16x16x32_bf16(a0[mf], b2[nf], c, 0, 0, 0);
                c = __builtin_amdgcn_mfma_f32_16x16x32_bf16(a2[mf], b0[nf], c, 0, 0, 0);
                c = __builtin_amdgcn_mfma_f32_16x16x32_bf16(a1[mf], b1[nf], c, 0, 0, 0);
                acc[mf][nf] = c;
            }
    }

    float* Cz = C + (size_t)z * (gridDim.x * 128) * ldc;
    const int rbase = (lane >> 4) * 4;
    const int lrow  = lane & 15;
#pragma unroll
    for (int mf = 0; mf < 4; mf++) {
#pragma unroll
        for (int nf = 0; nf < 4; nf++) {
            int col = nt * 128 + (wn_g + nf) * 16 + lrow;
#pragma unroll
            for (int r = 0; r < 4; r++) {
                int row = mt * 128 + (wm_g + mf) * 16 + rbase + r;
                Cz[(size_t)row * ldc + col] = acc[mf][nf][r];
            }
        }
    }
}

// ============================================================================
// Fragment-order conversions (3-way) for backbone / rpn
// ============================================================================

__global__ void k_convW3(const float* __restrict__ src,
                         ushort_t* __restrict__ D0, ushort_t* __restrict__ D1,
                         ushort_t* __restrict__ D2,
                         int K_LD, int k_base, int KS_TOT)
{
    int t = blockIdx.x * 256 + threadIdx.x;
    int per = KS_TOT << 9;
    int mt = t / per, rem = t - mt * per;
    int ks = rem >> 9, g = (rem >> 6) & 7, l = rem & 63;
    int m  = mt * 128 + g * 16 + (l & 15);
    int k0 = k_base + ks * 32 + ((l >> 4) << 3);
    const float* sp = src + (size_t)m * K_LD + k0;
    short8t v0, v1, v2;
#pragma unroll
    for (int j = 0; j < 8; j++) {
        unsigned short h, mm_, lo;
        split3_bf16(sp[j], h, mm_, lo);
        v0[j] = (short)h; v1[j] = (short)mm_; v2[j] = (short)lo;
    }
    *(short8t*)&D0[(size_t)t * 8] = v0;
    *(short8t*)&D1[(size_t)t * 8] = v1;
    *(short8t*)&D2[(size_t)t * 8] = v2;
}

__global__ void k_convX3(const float* __restrict__ X,
                         ushort_t* __restrict__ D0, ushort_t* __restrict__ D1,
                         ushort_t* __restrict__ D2)
{
    int t = blockIdx.x * 256 + threadIdx.x;   // 786432
    if (t >= 786432) return;
    int per = 96 << 9;
    int nt = t / per, rem = t - nt * per;
    int ks = rem >> 9, g = (rem >> 6) & 7, l = rem & 63;
    int n  = nt * 128 + g * 16 + (l & 15);
    int bimg = n >> 10, pn = n & 1023;
    int oy = pn >> 5, ox = pn & 31;
    int k0 = ks * 32 + ((l >> 4) << 3);
    int ic = k0 >> 10, kr = k0 & 1023;
    int ky = kr >> 5, kx0 = kr & 31;
    const float* sp = X + (((size_t)(bimg * 3 + ic) * 1024) + oy * 32 + ky) * 1024
                        + ox * 32 + kx0;
    short8t v0, v1, v2;
#pragma unroll
    for (int j = 0; j < 8; j++) {
        unsigned short h, mm_, lo;
        split3_bf16(sp[j], h, mm_, lo);
        v0[j] = (short)h; v1[j] = (short)mm_; v2[j] = (short)lo;
    }
    *(short8t*)&D0[(size_t)t * 8] = v0;
    *(short8t*)&D1[(size_t)t * 8] = v1;
    *(short8t*)&D2[(size_t)t * 8] = v2;
}

__global__ void k_convR3(const float* __restrict__ fm,
                         ushort_t* __restrict__ D0, ushort_t* __restrict__ D1,
                         ushort_t* __restrict__ D2, int k_base, int KS_TOT)
{
    int t = blockIdx.x * 256 + threadIdx.x;
    int per = KS_TOT << 9;
    if (t >= 16 * per) return;
    int nt = t / per, rem = t - nt * per;
    int ks = rem >> 9, g = (rem >> 6) & 7, l = rem & 63;
    int n  = nt * 128 + g * 16 + (l & 15);
    int bimg = n >> 10, pn = n & 1023;
    int y = pn >> 5, x = pn & 31;
    int kg = k_base + ks * 32 + ((l >> 4) << 3);
    int ic = kg / 9;
    int r9 = kg - ic * 9;
    int ky = r9 / 3;
    int kx = r9 - ky * 3;
    short8t v0, v1, v2;
#pragma unroll
    for (int j = 0; j < 8; j++) {
        int yy = y + ky - 1, xx = x + kx - 1;
        float v = 0.f;
        if (yy >= 0 && yy < 32 && xx >= 0 && xx < 32)
            v = fm[(((size_t)(bimg * 2048 + ic)) * 32 + yy) * 32 + xx];
        unsigned short h, mm_, lo;
        split3_bf16(v, h, mm_, lo);
        v0[j] = (short)h; v1[j] = (short)mm_; v2[j] = (short)lo;
        kx++;
        if (kx == 3) { kx = 0; ky++; if (ky == 3) { ky = 0; ic++; } }
    }
    *(short8t*)&D0[(size_t)t * 8] = v0;
    *(short8t*)&D1[(size_t)t * 8] = v1;
    *(short8t*)&D2[(size_t)t * 8] = v2;
}

// ---------------- plain bf16 convs for the fc1 path ----------

__global__ void k_convA(const float* __restrict__ fm, ushort_t* __restrict__ Aq)
{
    int t = blockIdx.x * 256 + threadIdx.x;    // 524288
    if (t >= 524288) return;
    int l  = t & 63;
    int g  = (t >> 6) & 7;
    int ks = (t >> 9) & 63;
    int mt = (t >> 15) & 7;
    int b  = t >> 18;
    int p  = mt * 128 + g * 16 + (l & 15);
    int c0 = ks * 32 + (l >> 4) * 8;
    const float* src = fm + ((size_t)(b * 2048 + c0)) * 1024 + p;
    short8t vh;
#pragma unroll
    for (int j = 0; j < 8; j++) vh[j] = (short)bf16_rne(src[(size_t)j * 1024]);
    *(short8t*)&Aq[(size_t)t * 8] = vh;
}

__global__ void k_convB(const float* __restrict__ W1, ushort_t* __restrict__ Bq)
{
    int t = blockIdx.x * 256 + threadIdx.x;    // 3211264
    if (t >= 3211264) return;
    int l  = t & 63;
    int h_ = (t >> 6) & 7;
    int ks = (t >> 9) & 63;
    int nt = t >> 15;
    int n  = nt * 128 + h_ * 16 + (l & 15);
    int c0 = ks * 32 + (l >> 4) * 8;
    const float* src = W1 + (size_t)c0 * 12544 + n;
    short8t vh;
#pragma unroll
    for (int j = 0; j < 8; j++) vh[j] = (short)bf16_rne(src[(size_t)j * 12544]);
    *(short8t*)&Bq[(size_t)t * 8] = vh;
}

// ============================================================================
// reduces
// ============================================================================

__global__ void k_backbone_reduce(const float* __restrict__ Pb, const float* __restrict__ bias,
                                  float* __restrict__ fm)
{
    int idx = blockIdx.x * 256 + threadIdx.x;
    if (idx >= 2048 * 2048) return;
    int oc = idx >> 11, n = idx & 2047;
    float s = Pb[(size_t)oc * 2048 + n]
            + Pb[((size_t)2048 + oc) * 2048 + n]
            + Pb[((size_t)4096 + oc) * 2048 + n];
    s = fmaxf(s + bias[oc], 0.f);
    int b = n >> 10, p = n & 1023;
    fm[((size_t)b * 2048 + oc) * 1024 + p] = s;
}

__global__ void k_rpn_acc(const float* __restrict__ Cp, float* __restrict__ Racc, int first)
{
    int idx = blockIdx.x * 256 + threadIdx.x;
    if (idx >= 512 * 2048) return;
    float s = 0.f;
#pragma unroll
    for (int z = 0; z < 8; z++)
        s += Cp[(size_t)z * 512 * 2048 + idx];
    Racc[idx] = first ? s : (Racc[idx] + s);
}

__global__ void k_rpn_final(const float* __restrict__ Racc, const float* __restrict__ bias,
                            float* __restrict__ hT)
{
    int idx = blockIdx.x * 256 + threadIdx.x;
    if (idx >= 512 * 2048) return;
    int oc = idx >> 11, n = idx & 2047;
    float s = fmaxf(Racc[(size_t)oc * 2048 + n] + bias[oc], 0.f);
    hT[n * 512 + oc] = s;
}

// ============================================================================
// small kernels
// ============================================================================

__global__ __launch_bounds__(64) void k_clsreg(
    const float* __restrict__ hT,
    const float* __restrict__ wc, const float* __restrict__ bc_,
    const float* __restrict__ wr, const float* __restrict__ br_,
    float* __restrict__ cls_raw, float* __restrict__ reg_raw)
{
    __shared__ float s[512];
    int n = blockIdx.x, tid = threadIdx.x;
    const float* hp = hT + n * 512;
    *(float4*)&s[tid * 8]     = *(const float4*)&hp[tid * 8];
    *(float4*)&s[tid * 8 + 4] = *(const float4*)&hp[tid * 8 + 4];
    __syncthreads();
    if (tid < 18) {
        float a = bc_[tid];
        const float* w = wc + tid * 512;
        for (int j = 0; j < 512; j++) a = fmaf(s[j], w[j], a);
        cls_raw[n * 18 + tid] = a;
    } else if (tid < 54) {
        int c = tid - 18;
        float a = br_[c];
        const float* w = wr + c * 512;
        for (int j = 0; j < 512; j++) a = fmaf(s[j], w[j], a);
        reg_raw[n * 36 + c] = a;
    }
}

__global__ void k_proposals(const float* __restrict__ cls_raw, const float* __restrict__ reg_raw,
                            float* __restrict__ proposals, float* __restrict__ scores)
{
    int t = blockIdx.x * 256 + threadIdx.x;
    if (t >= 2 * 9216) return;
    int b = t / 9216, n = t - b * 9216;
    int p = n / 9, a = n - p * 9;
    int pi = b * 1024 + p;
    float c0 = cls_raw[pi * 18 + 2 * a], c1 = cls_raw[pi * 18 + 2 * a + 1];
    float m = fmaxf(c0, c1);
    float e0 = expf(c0 - m), e1 = expf(c1 - m);
    float fg = e1 / (e0 + e1);
    float d0 = reg_raw[pi * 36 + 4 * a + 0];
    float d1 = reg_raw[pi * 36 + 4 * a + 1];
    float d2 = reg_raw[pi * 36 + 4 * a + 2];
    float d3 = reg_raw[pi * 36 + 4 * a + 3];
    int y = p >> 5, x = p & 31;
    const float sc[3] = {128.f, 256.f, 512.f};
    const float rt[3] = {0.5f, 1.f, 2.f};
    int si = a / 3, ri = a - si * 3;
    float sq = sqrtf(rt[ri]);
    float aw = sc[si] / sq, ah = sc[si] * sq;
    float cx = (x + 0.5f) * 32.f, cy = (y + 0.5f) * 32.f;
    float x1 = cx - 0.5f * aw, y1 = cy - 0.5f * ah;
    float x2 = cx + 0.5f * aw, y2 = cy + 0.5f * ah;
    float w = x2 - x1, h = y2 - y1;
    float ccx = x1 + 0.5f * w, ccy = y1 + 0.5f * h;
    float dw = fminf(fmaxf(d2, -4.f), 4.f), dh = fminf(fmaxf(d3, -4.f), 4.f);
    float ncx = ccx + d0 * w, ncy = ccy + d1 * h;
    float nw = w * expf(dw), nh = h * expf(dh);
    float px1 = fminf(fmaxf(ncx - 0.5f * nw, 0.f), 1023.f);
    float py1 = fminf(fmaxf(ncy - 0.5f * nh, 0.f), 1023.f);
    float px2 = fminf(fmaxf(ncx + 0.5f * nw, 0.f), 1023.f);
    float py2 = fminf(fmaxf(ncy + 0.5f * nh, 0.f), 1023.f);
    ((float4*)proposals)[t] = make_float4(px1, py1, px2, py2);
    scores[t] = fg;
}

// ============================================================================
// k_sortfull: init + full 16384 bitonic sort (LDS) + top-PRE gather, one
// dispatch, one block per batch. Same comparator network as the staged
// version; unique keys => identical output.
// ============================================================================

__global__ __launch_bounds__(1024) void k_sortfull(
    const float* __restrict__ scores, const float* __restrict__ proposals,
    float* __restrict__ topBoxes)
{
    extern __shared__ unsigned long long s[];
    const int b = blockIdx.x;
    const int tid = threadIdx.x;

    for (int i = tid; i < 16384; i += 1024) {
        unsigned long long key = 0ull;
        if (i < 9216) {
            unsigned bits = __float_as_uint(scores[b * 9216 + i]);
            key = ((unsigned long long)bits << 32) | (unsigned)(~i);
        }
        s[i] = key;
    }
    __syncthreads();

    for (unsigned k = 2; k <= 16384; k <<= 1) {
        for (unsigned j = k >> 1; j > 0; j >>= 1) {
#pragma unroll
            for (int t = 0; t < 8; t++) {
                unsigned p = tid + t * 1024;
                unsigned i = ((p & ~(j - 1)) << 1) | (p & (j - 1));
                unsigned l = i | j;
                bool up = ((i & k) == 0);
                unsigned long long a = s[i], c = s[l];
                bool sw = up ? (c > a) : (a > c);
                if (sw) { s[i] = c; s[l] = a; }
            }
            __syncthreads();
        }
    }

    for (int pos = tid; pos < PRE; pos += 1024) {
        unsigned long long key = s[pos];
        unsigned idx = ~(unsigned)(key & 0xFFFFFFFFull);
        ((float4*)topBoxes)[b * PRE + pos] = ((const float4*)proposals)[b * 9216 + idx];
    }
}

__global__ __launch_bounds__(64) void k_iou(const float* __restrict__ topBoxes,
                                            unsigned* __restrict__ mask)
{
    int blk = blockIdx.x;
    int b = blk / PRE, i = blk - b * PRE;
    int lane = threadIdx.x;
    const float4* boxes = ((const float4*)topBoxes) + b * PRE;
    float4 bi = boxes[i];
    float area_a = (bi.z - bi.x) * (bi.w - bi.y);
    if (lane < 63) {
        unsigned wbits = 0u;
        for (int t = 0; t < 32; t++) {
            int j = lane * 32 + t;
            if (j < PRE && j > i) {
                float4 bj = boxes[j];
                float area_b = (bj.z - bj.x) * (bj.w - bj.y);
                float ltx = fmaxf(bi.x, bj.x), lty = fmaxf(bi.y, bj.y);
                float rbx = fminf(bi.z, bj.z), rby = fminf(bi.w, bj.w);
                float iw = fmaxf(rbx - ltx, 0.f), ih = fmaxf(rby - lty, 0.f);
                float inter = iw * ih;
                float iou = inter / (area_a + area_b - inter + 1e-9f);
                if (iou > 0.7f) wbits |= (1u << t);
            }
        }
        mask[(b * PRE + i) * 63 + lane] = wbits;
    }
}

__global__ __launch_bounds__(64) void k_compact(const unsigned* __restrict__ keep,
                                                const float* __restrict__ topBoxes,
                                                float* __restrict__ props, float* __restrict__ validf)
{
    int b = blockIdx.x;
    int lane = threadIdx.x;
    unsigned kw = (lane < 63) ? keep[b * 63 + lane] : 0u;
    int cnt = __popc(kw);
    int inc = cnt;
    for (int off = 1; off < 64; off <<= 1) {
        int v = __shfl_up(inc, off);
        if (lane >= off) inc += v;
    }
    int excl = inc - cnt;
    for (int t = 0; t < 32; t++) {
        if ((kw >> t) & 1u) {
            int rank = excl + __popc(kw & ((1u << t) - 1u));
            if (rank < TOPN) {
                int j = lane * 32 + t;
                ((float4*)props)[b * TOPN + rank] = ((const float4*)topBoxes)[b * PRE + j];
                validf[b * TOPN + rank] = 1.0f;
            }
        }
    }
}

// ============================================================================
// k_combhead: roico + combine + head fused. One block per ROI (2*TOPN).
// Identical FP operations to the separate kernels.
// ============================================================================

__global__ __launch_bounds__(256) void k_combhead(
    const ushort_t* __restrict__ T, const float* __restrict__ props,
    const float* __restrict__ validf, const float* __restrict__ b1,
    const float* __restrict__ w2, const float* __restrict__ b2,
    const float* __restrict__ wc, const float* __restrict__ bcb,
    const float* __restrict__ wr, const float* __restrict__ brb,
    float* __restrict__ out)
{
    int g = blockIdx.x;               // b*TOPN + n
    int b = g / TOPN;
    int tid = threadIdx.x;
    __shared__ float rc[48];
    __shared__ float s1[256], s2v[256], rg[4];

    float vm = validf[g];
    // roico phase (same math as k_roico)
    if (vm != 0.f && tid < 14) {
        float4 box = ((const float4*)props)[g];
        const float scale = 1.f / 32.f;
        float x1 = box.x * scale, y1 = box.y * scale;
        float x2 = box.z * scale, y2 = box.w * scale;
        if (tid < 7) {
            int u = tid;
            float xs = x1 + (u + 0.5f) * (x2 - x1) / 7.f;
            xs = fminf(fmaxf(xs, 0.f), 31.f);
            float x0f = floorf(xs);
            rc[u] = x0f;
            rc[7 + u] = fminf(x0f + 1.f, 31.f);
            rc[14 + u] = xs - x0f;
        } else {
            int u = tid - 7;
            float ys = y1 + (u + 0.5f) * (y2 - y1) / 7.f;
            ys = fminf(fmaxf(ys, 0.f), 31.f);
            float y0f = floorf(ys);
            rc[21 + u] = y0f;
            rc[28 + u] = fminf(y0f + 1.f, 31.f);
            rc[35 + u] = ys - y0f;
        }
    }
    __syncthreads();

    // combine phase (same math as k_combine)
    float acc = 0.f;
    const ushort_t* Tb = T + (size_t)b * 12845056;
    if (vm != 0.f) {
#pragma unroll
        for (int py = 0; py < 7; py++) {
            int y0 = (int)rc[21 + py], y1 = (int)rc[28 + py];
            float wy = rc[35 + py];
#pragma unroll
            for (int px = 0; px < 7; px++) {
                int x0 = (int)rc[px], x1 = (int)rc[7 + px];
                float wx = rc[14 + px];
                int qo = (py * 7 + px) * 256 + tid;
                float f00 = __uint_as_float((unsigned)Tb[(size_t)(y0 * 32 + x0) * 12544 + qo] << 16);
                float f01 = __uint_as_float((unsigned)Tb[(size_t)(y0 * 32 + x1) * 12544 + qo] << 16);
                float f10 = __uint_as_float((unsigned)Tb[(size_t)(y1 * 32 + x0) * 12544 + qo] << 16);
                float f11 = __uint_as_float((unsigned)Tb[(size_t)(y1 * 32 + x1) * 12544 + qo] << 16);
                acc += f00 * (1.f - wy) * (1.f - wx) + f01 * (1.f - wy) * wx
                     + f10 * wy * (1.f - wx) + f11 * wy * wx;
            }
        }
    }
    s1[tid] = fmaxf(acc + b1[tid], 0.f);
    __syncthreads();

    // head phase (same math as k_head)
    float a2 = b2[tid];
    for (int j = 0; j < 256; j++) a2 = fmaf(s1[j], w2[j * 256 + tid], a2);
    s2v[tid] = fmaxf(a2, 0.f);
    __syncthreads();
    if (tid < 21) {
        float a = bcb[tid];
        for (int j = 0; j < 256; j++) a = fmaf(s2v[j], wc[j * 21 + tid], a);
        out[8000 + g * 21 + tid] = a * vm;
    } else if (tid >= 32 && tid < 36) {
        int r = tid - 32;
        float a = brb[r];
        for (int j = 0; j < 256; j++) a = fmaf(s2v[j], wr[j * 4 + r], a);
        rg[r] = a * vm;
    }
    __syncthreads();
    if (tid == 0) {
        float4 pb = ((const float4*)props)[g];
        float w = pb.z - pb.x, h = pb.w - pb.y;
        float cx = pb.x + 0.5f * w, cy = pb.y + 0.5f * h;
        float dw = fminf(fmaxf(rg[2], -4.f), 4.f), dh = fminf(fmaxf(rg[3], -4.f), 4.f);
        float ncx = cx + rg[0] * w, ncy = cy + rg[1] * h;
        float nw = w * expf(dw), nh = h * expf(dh);
        float x1 = fminf(fmaxf(ncx - 0.5f * nw, 0.f), 1023.f);
        float y1 = fminf(fmaxf(ncy - 0.5f * nh, 0.f), 1023.f);
        float x2 = fminf(fmaxf(ncx + 0.5f * nw, 0.f), 1023.f);
        float y2 = fminf(fmaxf(ncy + 0.5f * nh, 0.f), 1023.f);
        ((float4*)out)[g] = make_float4(x1 * vm, y1 * vm, x2 * vm, y2 * vm);
    }
}

// ============================================================================
// launcher
// ============================================================================

extern "C" void kernel_launch(void* const* d_in, const int* in_sizes, int n_in,
                              void* d_out, int out_size, void* d_ws, size_t ws_size,
                              hipStream_t stream)
{
    const float* x          = (const float*)d_in[0];
    const float* backbone_w = (const float*)d_in[1];
    const float* backbone_b = (const float*)d_in[2];
    const float* rpn_w      = (const float*)d_in[3];
    const float* rpn_b      = (const float*)d_in[4];
    const float* rpn_cls_w  = (const float*)d_in[5];
    const float* rpn_cls_b  = (const float*)d_in[6];
    const float* rpn_reg_w  = (const float*)d_in[7];
    const float* rpn_reg_b  = (const float*)d_in[8];
    const float* fc1_w      = (const float*)d_in[9];
    const float* fc1_b      = (const float*)d_in[10];
    const float* fc2_w      = (const float*)d_in[11];
    const float* fc2_b      = (const float*)d_in[12];
    const float* cls_w      = (const float*)d_in[13];
    const float* cls_b      = (const float*)d_in[14];
    const float* reg_w      = (const float*)d_in[15];
    const float* reg_b      = (const float*)d_in[16];
    float* out = (float*)d_out;

    char* base = (char*)d_ws;
    size_t off = 0;
    auto alloc = [&](size_t bytes) {
        void* p = base + off;
        off = (off + bytes + 255) & ~(size_t)255;
        return p;
    };
    float* fm        = (float*)alloc((size_t)2 * 2048 * 1024 * 4);
    float* Cp        = (float*)alloc((size_t)16 * 512 * 2048 * 4);
    float* hT        = (float*)alloc(2048u * 512 * 4);
    float* Racc      = (float*)alloc(512u * 2048 * 4);
    float* cls_raw   = (float*)alloc(2048u * 18 * 4);
    float* reg_raw   = (float*)alloc(2048u * 36 * 4);
    float* proposals = (float*)alloc(2u * 9216 * 4 * 4);
    float* scores    = (float*)alloc(2u * 9216 * 4);
    unsigned long long* keys = (unsigned long long*)alloc(2u * 16384 * 8);
    float* topBoxes  = (float*)alloc(2u * PRE * 4 * 4);
    unsigned* ioumask= (unsigned*)alloc(2u * PRE * 63 * 4);
    unsigned* keep   = (unsigned*)alloc(2u * 63 * 4);
    float* props     = (float*)alloc(2u * TOPN * 4 * 4);
    float* validf    = (float*)alloc(2u * TOPN * 4);
    float* roico     = (float*)alloc(2u * TOPN * 48 * 4);
    char*  arena     = (char*)alloc(119537664);
    float* h1        = (float*)alloc(2u * TOPN * 256 * 4);
    (void)keys; (void)roico; (void)h1;

    // phase 1: backbone frags (3-way)
    ushort_t* Wb0 = (ushort_t*)(arena);
    ushort_t* Wb1 = (ushort_t*)(arena + 12582912);
    ushort_t* Wb2 = (ushort_t*)(arena + 25165824);
    ushort_t* Xf0 = (ushort_t*)(arena + 37748736);
    ushort_t* Xf1 = (ushort_t*)(arena + 50331648);
    ushort_t* Xf2 = (ushort_t*)(arena + 62914560);
    // phase 2: rpn frags (per K-quarter)
    ushort_t* Wr0 = (ushort_t*)(arena);
    ushort_t* Wr1 = (ushort_t*)(arena + 4718592);
    ushort_t* Wr2 = (ushort_t*)(arena + 9437184);
    ushort_t* Rb0 = (ushort_t*)(arena + 14155776);
    ushort_t* Rb1 = (ushort_t*)(arena + 33030144);
    ushort_t* Rb2 = (ushort_t*)(arena + 51904512);
    // phase 3: fc1 frags (plain bf16) + bf16 T
    ushort_t* Aq   = (ushort_t*)(arena);                  // 8.4 MB
    ushort_t* Tbuf = (ushort_t*)(arena + 16777216);       // 51.4 MB
    ushort_t* Bq   = (ushort_t*)Cp;                       // 51.4 MB alias

    k_convW3<<<3072, 256, 0, stream>>>(backbone_w, Wb0, Wb1, Wb2, 3072, 0, 96);
    k_convX3<<<3072, 256, 0, stream>>>(x, Xf0, Xf1, Xf2);
    k_gemm6<<<dim3(16, 16, 3), 256, 0, stream>>>(Wb0, Wb1, Wb2, Xf0, Xf1, Xf2,
                                                 Cp, 32, 96, 2048);
    k_backbone_reduce<<<(2048 * 2048) / 256, 256, 0, stream>>>(Cp, backbone_b, fm);

    for (int q = 0; q < 4; q++) {
        k_convW3<<<1152, 256, 0, stream>>>(rpn_w, Wr0, Wr1, Wr2, 18432, q * 4608, 144);
        k_convR3<<<4608, 256, 0, stream>>>(fm, Rb0, Rb1, Rb2, q * 4608, 144);
        k_gemm6<<<dim3(4, 16, 8), 256, 0, stream>>>(Wr0, Wr1, Wr2, Rb0, Rb1, Rb2,
                                                    Cp, 18, 144, 2048);
        k_rpn_acc<<<4096, 256, 0, stream>>>(Cp, Racc, q == 0 ? 1 : 0);
    }
    k_rpn_final<<<4096, 256, 0, stream>>>(Racc, rpn_b, hT);

    k_convB<<<12544, 256, 0, stream>>>(fc1_w, Bq);
    k_convA<<<2048, 256, 0, stream>>>(fm, Aq);

    k_clsreg<<<2048, 64, 0, stream>>>(hT, rpn_cls_w, rpn_cls_b, rpn_reg_w, rpn_reg_b,
                                      cls_raw, reg_raw);
    k_proposals<<<(2 * 9216 + 255) / 256, 256, 0, stream>>>(cls_raw, reg_raw, proposals, scores);

    // fused init + bitonic sort + gather (1 dispatch, 128 KB dynamic LDS)
    k_sortfull<<<2, 1024, 131072, stream>>>(scores, proposals, topBoxes);

    k_iou<<<2 * PRE, 64, 0, stream>>>(topBoxes, ioumask);
    hipMemsetAsync(props, 0, 2u * TOPN * 4 * 4, stream);
    hipMemsetAsync(validf, 0, 2u * TOPN * 4, stream);

    // fused: greedy NMS (blocks 0-1, start first) + fc1 GEMM (blocks 2-1569)
    k_fused<<<1570, 256, 0, stream>>>(Aq, Bq, Tbuf, ioumask, keep);

    k_compact<<<2, 64, 0, stream>>>(keep, topBoxes, props, validf);
    k_combhead<<<2 * TOPN, 256, 0, stream>>>(Tbuf, props, validf, fc1_b,
                                             fc2_w, fc2_b, cls_w, cls_b, reg_w, reg_b,
                                             out);
}

// Round 18
// 919.753 us; speedup vs baseline: 1.0647x; 1.0647x over previous
//
#include <hip/hip_runtime.h>

#define PRE 2000
#define TOPN 1000

typedef __attribute__((ext_vector_type(8))) short short8t;
typedef __attribute__((ext_vector_type(4))) float f32x4;
typedef unsigned short ushort_t;

__device__ inline unsigned short bf16_rne(float x) {
    unsigned u = __float_as_uint(x);
    unsigned r = u + 0x7FFFu + ((u >> 16) & 1u);
    return (unsigned short)(r >> 16);
}

__device__ inline void split3_bf16(float x, unsigned short& h, unsigned short& m,
                                   unsigned short& l) {
    h = bf16_rne(x);
    float hf = __uint_as_float((unsigned)h << 16);
    float r1 = x - hf;
    m = bf16_rne(r1);
    float mf = __uint_as_float((unsigned)m << 16);
    l = bf16_rne(r1 - mf);
}

// ============================================================================
// k_fused: blocks 0..1 = greedy NMS v2 (start first, hide under GEMM);
// blocks 2..1569 = fc1 T-matrix GEMM (plain bf16, XCD swizzle, bf16 out).
// ============================================================================

__global__ __launch_bounds__(256, 4) void k_fused(
    const ushort_t* __restrict__ Aq, const ushort_t* __restrict__ Bq,
    ushort_t* __restrict__ T,
    const unsigned* __restrict__ mask, unsigned* __restrict__ keep)
{
    if (blockIdx.x < 2) {
        if (threadIdx.x >= 64) return;
        const int b = blockIdx.x;
        const int lane = threadIdx.x;
        unsigned kw = (lane < 62) ? 0xFFFFFFFFu : (lane == 62 ? 0xFFFFu : 0u);
        const unsigned* mbase = mask + (size_t)b * PRE * 63;
        bool ld = (lane < 63);

        unsigned buf[16];
#pragma unroll
        for (int d = 0; d < 16; d++)
            buf[d] = ld ? mbase[(size_t)d * 63 + lane] : 0u;

        for (int g = 0; g < PRE; g += 16) {
#pragma unroll
            for (int d = 0; d < 16; d++) {
                int i = g + d;
                unsigned row = buf[d];
                int ip = i + 16;
                buf[d] = (ld && ip < PRE) ? mbase[(size_t)ip * 63 + lane] : 0u;
                unsigned wv = (unsigned)__shfl((int)kw, i >> 5);
                if ((wv >> (i & 31)) & 1u)
                    kw &= ~row;
            }
        }
        if (lane < 63) keep[b * 63 + lane] = kw;
        return;
    }

    const int flat = blockIdx.x - 2;         // 0..1567
    const int xcd  = flat & 7;
    const int jj   = flat >> 3;
    const int wg   = xcd * 196 + jj;
    const int b    = wg / 784;
    const int rem  = wg - b * 784;
    const int nt   = rem >> 3;               // 0..97
    const int mt   = rem & 7;                // 0..7

    const int tid  = threadIdx.x;
    const int wid  = tid >> 6, lane = tid & 63;
    const int wm_g = (wid >> 1) * 4;
    const int wn_g = (wid & 1) * 4;

    f32x4 acc[4][4];
#pragma unroll
    for (int i = 0; i < 4; i++)
#pragma unroll
        for (int j = 0; j < 4; j++) acc[i][j] = (f32x4){0.f, 0.f, 0.f, 0.f};

    const size_t aoff = (size_t)b * 2097152 + (size_t)mt * 262144
                      + (size_t)wm_g * 512 + (size_t)lane * 8;
    const size_t boff = (size_t)nt * 262144 + (size_t)wn_g * 512 + (size_t)lane * 8;
    const ushort_t* pA = Aq + aoff;
    const ushort_t* pB = Bq + boff;

    for (int ks = 0; ks < 64; ks++) {
        const size_t so = (size_t)ks * 4096;
        short8t a[4], bb[4];
#pragma unroll
        for (int f = 0; f < 4; f++) {
            a[f]  = *(const short8t*)(pA + so + f * 512);
            bb[f] = *(const short8t*)(pB + so + f * 512);
        }
#pragma unroll
        for (int mf = 0; mf < 4; mf++)
#pragma unroll
            for (int nf = 0; nf < 4; nf++)
                acc[mf][nf] = __builtin_amdgcn_mfma_f32_16x16x32_bf16(
                    a[mf], bb[nf], acc[mf][nf], 0, 0, 0);
    }

    ushort_t* Tb = T + (size_t)b * 12845056;   // 1024*12544
    const int rbase = (lane >> 4) * 4;
    const int lrow  = lane & 15;
#pragma unroll
    for (int mf = 0; mf < 4; mf++) {
#pragma unroll
        for (int nf = 0; nf < 4; nf++) {
            int col = nt * 128 + (wn_g + nf) * 16 + lrow;
#pragma unroll
            for (int r = 0; r < 4; r++) {
                int row = mt * 128 + (wm_g + mf) * 16 + rbase + r;
                Tb[(size_t)row * 12544 + col] = bf16_rne(acc[mf][nf][r]);
            }
        }
    }
}

// ============================================================================
// k_gemm6: 3-way split (6 products ~ f32 accuracy) — rank-critical GEMMs.
// ============================================================================

__global__ __launch_bounds__(256, 2) void k_gemm6(
    const ushort_t* __restrict__ A0, const ushort_t* __restrict__ A1,
    const ushort_t* __restrict__ A2,
    const ushort_t* __restrict__ B0, const ushort_t* __restrict__ B1,
    const ushort_t* __restrict__ B2,
    float* __restrict__ C, int ks_per_z, int KS_TOT, int ldc)
{
    const int tid  = threadIdx.x;
    const int wid  = tid >> 6, lane = tid & 63;
    const int wm_g = (wid >> 1) * 4;
    const int wn_g = (wid & 1) * 4;
    const int mt   = blockIdx.x;
    const int nt   = blockIdx.y;
    const int z    = blockIdx.z;

    f32x4 acc[4][4];
#pragma unroll
    for (int i = 0; i < 4; i++)
#pragma unroll
        for (int j = 0; j < 4; j++) acc[i][j] = (f32x4){0.f, 0.f, 0.f, 0.f};

    const size_t aoff = (size_t)mt * KS_TOT * 4096 + (size_t)wm_g * 512 + (size_t)lane * 8;
    const size_t boff = (size_t)nt * KS_TOT * 4096 + (size_t)wn_g * 512 + (size_t)lane * 8;
    const ushort_t* pA0 = A0 + aoff;
    const ushort_t* pA1 = A1 + aoff;
    const ushort_t* pA2 = A2 + aoff;
    const ushort_t* pB0 = B0 + boff;
    const ushort_t* pB1 = B1 + boff;
    const ushort_t* pB2 = B2 + boff;

    const int ks0 = z * ks_per_z;
    for (int ks = ks0; ks < ks0 + ks_per_z; ks++) {
        const size_t so = (size_t)ks * 4096;
        short8t a0[4], a1[4], a2[4], b0[4], b1[4], b2[4];
#pragma unroll
        for (int f = 0; f < 4; f++) {
            a0[f] = *(const short8t*)(pA0 + so + f * 512);
            a1[f] = *(const short8t*)(pA1 + so + f * 512);
            a2[f] = *(const short8t*)(pA2 + so + f * 512);
            b0[f] = *(const short8t*)(pB0 + so + f * 512);
            b1[f] = *(const short8t*)(pB1 + so + f * 512);
            b2[f] = *(const short8t*)(pB2 + so + f * 512);
        }
#pragma unroll
        for (int mf = 0; mf < 4; mf++)
#pragma unroll
            for (int nf = 0; nf < 4; nf++) {
                f32x4 c = acc[mf][nf];
                c = __builtin_amdgcn_mfma_f32_16x16x32_bf16(a0[mf], b0[nf], c, 0, 0, 0);
                c = __builtin_amdgcn_mfma_f32_16x16x32_bf16(a0[mf], b1[nf], c, 0, 0, 0);
                c = __builtin_amdgcn_mfma_f32_16x16x32_bf16(a1[mf], b0[nf], c, 0, 0, 0);
                c = __builtin_amdgcn_mfma_f32_16x16x32_bf16(a0[mf], b2[nf], c, 0, 0, 0);
                c = __builtin_amdgcn_mfma_f32_16x16x32_bf16(a2[mf], b0[nf], c, 0, 0, 0);
                c = __builtin_amdgcn_mfma_f32_16x16x32_bf16(a1[mf], b1[nf], c, 0, 0, 0);
                acc[mf][nf] = c;
            }
    }

    float* Cz = C + (size_t)z * (gridDim.x * 128) * ldc;
    const int rbase = (lane >> 4) * 4;
    const int lrow  = lane & 15;
#pragma unroll
    for (int mf = 0; mf < 4; mf++) {
#pragma unroll
        for (int nf = 0; nf < 4; nf++) {
            int col = nt * 128 + (wn_g + nf) * 16 + lrow;
#pragma unroll
            for (int r = 0; r < 4; r++) {
                int row = mt * 128 + (wm_g + mf) * 16 + rbase + r;
                Cz[(size_t)row * ldc + col] = acc[mf][nf][r];
            }
        }
    }
}

// ============================================================================
// Fragment-order conversions (3-way) for backbone / rpn
// ============================================================================

__global__ void k_convW3(const float* __restrict__ src,
                         ushort_t* __restrict__ D0, ushort_t* __restrict__ D1,
                         ushort_t* __restrict__ D2,
                         int K_LD, int k_base, int KS_TOT)
{
    int t = blockIdx.x * 256 + threadIdx.x;
    int per = KS_TOT << 9;
    int mt = t / per, rem = t - mt * per;
    int ks = rem >> 9, g = (rem >> 6) & 7, l = rem & 63;
    int m  = mt * 128 + g * 16 + (l & 15);
    int k0 = k_base + ks * 32 + ((l >> 4) << 3);
    const float* sp = src + (size_t)m * K_LD + k0;
    short8t v0, v1, v2;
#pragma unroll
    for (int j = 0; j < 8; j++) {
        unsigned short h, mm_, lo;
        split3_bf16(sp[j], h, mm_, lo);
        v0[j] = (short)h; v1[j] = (short)mm_; v2[j] = (short)lo;
    }
    *(short8t*)&D0[(size_t)t * 8] = v0;
    *(short8t*)&D1[(size_t)t * 8] = v1;
    *(short8t*)&D2[(size_t)t * 8] = v2;
}

__global__ void k_convX3(const float* __restrict__ X,
                         ushort_t* __restrict__ D0, ushort_t* __restrict__ D1,
                         ushort_t* __restrict__ D2)
{
    int t = blockIdx.x * 256 + threadIdx.x;   // 786432
    if (t >= 786432) return;
    int per = 96 << 9;
    int nt = t / per, rem = t - nt * per;
    int ks = rem >> 9, g = (rem >> 6) & 7, l = rem & 63;
    int n  = nt * 128 + g * 16 + (l & 15);
    int bimg = n >> 10, pn = n & 1023;
    int oy = pn >> 5, ox = pn & 31;
    int k0 = ks * 32 + ((l >> 4) << 3);
    int ic = k0 >> 10, kr = k0 & 1023;
    int ky = kr >> 5, kx0 = kr & 31;
    const float* sp = X + (((size_t)(bimg * 3 + ic) * 1024) + oy * 32 + ky) * 1024
                        + ox * 32 + kx0;
    short8t v0, v1, v2;
#pragma unroll
    for (int j = 0; j < 8; j++) {
        unsigned short h, mm_, lo;
        split3_bf16(sp[j], h, mm_, lo);
        v0[j] = (short)h; v1[j] = (short)mm_; v2[j] = (short)lo;
    }
    *(short8t*)&D0[(size_t)t * 8] = v0;
    *(short8t*)&D1[(size_t)t * 8] = v1;
    *(short8t*)&D2[(size_t)t * 8] = v2;
}

__global__ void k_convR3(const float* __restrict__ fm,
                         ushort_t* __restrict__ D0, ushort_t* __restrict__ D1,
                         ushort_t* __restrict__ D2, int k_base, int KS_TOT)
{
    int t = blockIdx.x * 256 + threadIdx.x;
    int per = KS_TOT << 9;
    if (t >= 16 * per) return;
    int nt = t / per, rem = t - nt * per;
    int ks = rem >> 9, g = (rem >> 6) & 7, l = rem & 63;
    int n  = nt * 128 + g * 16 + (l & 15);
    int bimg = n >> 10, pn = n & 1023;
    int y = pn >> 5, x = pn & 31;
    int kg = k_base + ks * 32 + ((l >> 4) << 3);
    int ic = kg / 9;
    int r9 = kg - ic * 9;
    int ky = r9 / 3;
    int kx = r9 - ky * 3;
    short8t v0, v1, v2;
#pragma unroll
    for (int j = 0; j < 8; j++) {
        int yy = y + ky - 1, xx = x + kx - 1;
        float v = 0.f;
        if (yy >= 0 && yy < 32 && xx >= 0 && xx < 32)
            v = fm[(((size_t)(bimg * 2048 + ic)) * 32 + yy) * 32 + xx];
        unsigned short h, mm_, lo;
        split3_bf16(v, h, mm_, lo);
        v0[j] = (short)h; v1[j] = (short)mm_; v2[j] = (short)lo;
        kx++;
        if (kx == 3) { kx = 0; ky++; if (ky == 3) { ky = 0; ic++; } }
    }
    *(short8t*)&D0[(size_t)t * 8] = v0;
    *(short8t*)&D1[(size_t)t * 8] = v1;
    *(short8t*)&D2[(size_t)t * 8] = v2;
}

// ---------------- plain bf16 convs for the fc1 path ----------

__global__ void k_convA(const float* __restrict__ fm, ushort_t* __restrict__ Aq)
{
    int t = blockIdx.x * 256 + threadIdx.x;    // 524288
    if (t >= 524288) return;
    int l  = t & 63;
    int g  = (t >> 6) & 7;
    int ks = (t >> 9) & 63;
    int mt = (t >> 15) & 7;
    int b  = t >> 18;
    int p  = mt * 128 + g * 16 + (l & 15);
    int c0 = ks * 32 + (l >> 4) * 8;
    const float* src = fm + ((size_t)(b * 2048 + c0)) * 1024 + p;
    short8t vh;
#pragma unroll
    for (int j = 0; j < 8; j++) vh[j] = (short)bf16_rne(src[(size_t)j * 1024]);
    *(short8t*)&Aq[(size_t)t * 8] = vh;
}

__global__ void k_convB(const float* __restrict__ W1, ushort_t* __restrict__ Bq)
{
    int t = blockIdx.x * 256 + threadIdx.x;    // 3211264
    if (t >= 3211264) return;
    int l  = t & 63;
    int h_ = (t >> 6) & 7;
    int ks = (t >> 9) & 63;
    int nt = t >> 15;
    int n  = nt * 128 + h_ * 16 + (l & 15);
    int c0 = ks * 32 + (l >> 4) * 8;
    const float* src = W1 + (size_t)c0 * 12544 + n;
    short8t vh;
#pragma unroll
    for (int j = 0; j < 8; j++) vh[j] = (short)bf16_rne(src[(size_t)j * 12544]);
    *(short8t*)&Bq[(size_t)t * 8] = vh;
}

// ============================================================================
// reduces
// ============================================================================

__global__ void k_backbone_reduce(const float* __restrict__ Pb, const float* __restrict__ bias,
                                  float* __restrict__ fm)
{
    int idx = blockIdx.x * 256 + threadIdx.x;
    if (idx >= 2048 * 2048) return;
    int oc = idx >> 11, n = idx & 2047;
    float s = Pb[(size_t)oc * 2048 + n]
            + Pb[((size_t)2048 + oc) * 2048 + n]
            + Pb[((size_t)4096 + oc) * 2048 + n];
    s = fmaxf(s + bias[oc], 0.f);
    int b = n >> 10, p = n & 1023;
    fm[((size_t)b * 2048 + oc) * 1024 + p] = s;
}

__global__ void k_rpn_acc(const float* __restrict__ Cp, float* __restrict__ Racc, int first)
{
    int idx = blockIdx.x * 256 + threadIdx.x;
    if (idx >= 512 * 2048) return;
    float s = 0.f;
#pragma unroll
    for (int z = 0; z < 8; z++)
        s += Cp[(size_t)z * 512 * 2048 + idx];
    Racc[idx] = first ? s : (Racc[idx] + s);
}

__global__ void k_rpn_final(const float* __restrict__ Racc, const float* __restrict__ bias,
                            float* __restrict__ hT)
{
    int idx = blockIdx.x * 256 + threadIdx.x;
    if (idx >= 512 * 2048) return;
    int oc = idx >> 11, n = idx & 2047;
    float s = fmaxf(Racc[(size_t)oc * 2048 + n] + bias[oc], 0.f);
    hT[n * 512 + oc] = s;
}

// ============================================================================
// small kernels
// ============================================================================

__global__ __launch_bounds__(64) void k_clsreg(
    const float* __restrict__ hT,
    const float* __restrict__ wc, const float* __restrict__ bc_,
    const float* __restrict__ wr, const float* __restrict__ br_,
    float* __restrict__ cls_raw, float* __restrict__ reg_raw)
{
    __shared__ float s[512];
    int n = blockIdx.x, tid = threadIdx.x;
    const float* hp = hT + n * 512;
    *(float4*)&s[tid * 8]     = *(const float4*)&hp[tid * 8];
    *(float4*)&s[tid * 8 + 4] = *(const float4*)&hp[tid * 8 + 4];
    __syncthreads();
    if (tid < 18) {
        float a = bc_[tid];
        const float* w = wc + tid * 512;
        for (int j = 0; j < 512; j++) a = fmaf(s[j], w[j], a);
        cls_raw[n * 18 + tid] = a;
    } else if (tid < 54) {
        int c = tid - 18;
        float a = br_[c];
        const float* w = wr + c * 512;
        for (int j = 0; j < 512; j++) a = fmaf(s[j], w[j], a);
        reg_raw[n * 36 + c] = a;
    }
}

__global__ void k_proposals(const float* __restrict__ cls_raw, const float* __restrict__ reg_raw,
                            float* __restrict__ proposals, float* __restrict__ scores)
{
    int t = blockIdx.x * 256 + threadIdx.x;
    if (t >= 2 * 9216) return;
    int b = t / 9216, n = t - b * 9216;
    int p = n / 9, a = n - p * 9;
    int pi = b * 1024 + p;
    float c0 = cls_raw[pi * 18 + 2 * a], c1 = cls_raw[pi * 18 + 2 * a + 1];
    float m = fmaxf(c0, c1);
    float e0 = expf(c0 - m), e1 = expf(c1 - m);
    float fg = e1 / (e0 + e1);
    float d0 = reg_raw[pi * 36 + 4 * a + 0];
    float d1 = reg_raw[pi * 36 + 4 * a + 1];
    float d2 = reg_raw[pi * 36 + 4 * a + 2];
    float d3 = reg_raw[pi * 36 + 4 * a + 3];
    int y = p >> 5, x = p & 31;
    const float sc[3] = {128.f, 256.f, 512.f};
    const float rt[3] = {0.5f, 1.f, 2.f};
    int si = a / 3, ri = a - si * 3;
    float sq = sqrtf(rt[ri]);
    float aw = sc[si] / sq, ah = sc[si] * sq;
    float cx = (x + 0.5f) * 32.f, cy = (y + 0.5f) * 32.f;
    float x1 = cx - 0.5f * aw, y1 = cy - 0.5f * ah;
    float x2 = cx + 0.5f * aw, y2 = cy + 0.5f * ah;
    float w = x2 - x1, h = y2 - y1;
    float ccx = x1 + 0.5f * w, ccy = y1 + 0.5f * h;
    float dw = fminf(fmaxf(d2, -4.f), 4.f), dh = fminf(fmaxf(d3, -4.f), 4.f);
    float ncx = ccx + d0 * w, ncy = ccy + d1 * h;
    float nw = w * expf(dw), nh = h * expf(dh);
    float px1 = fminf(fmaxf(ncx - 0.5f * nw, 0.f), 1023.f);
    float py1 = fminf(fmaxf(ncy - 0.5f * nh, 0.f), 1023.f);
    float px2 = fminf(fmaxf(ncx + 0.5f * nw, 0.f), 1023.f);
    float py2 = fminf(fmaxf(ncy + 0.5f * nh, 0.f), 1023.f);
    ((float4*)proposals)[t] = make_float4(px1, py1, px2, py2);
    scores[t] = fg;
}

// ---------------- staged sort (round-16 proven form) ----------------

__global__ void k_sort_init(const float* __restrict__ scores, unsigned long long* __restrict__ keys)
{
    int t = blockIdx.x * 256 + threadIdx.x;
    if (t >= 2 * 16384) return;
    int b = t >> 14, i = t & 16383;
    unsigned long long key = 0ull;
    if (i < 9216) {
        unsigned bits = __float_as_uint(scores[b * 9216 + i]);
        key = ((unsigned long long)bits << 32) | (unsigned)(~i);
    }
    keys[t] = key;
}

__global__ __launch_bounds__(512) void k_sort_lds(unsigned long long* __restrict__ keys,
                                                  int kmode, int wcount)
{
    __shared__ unsigned long long s[4096];
    int b = blockIdx.x / wcount, w = blockIdx.x % wcount;
    unsigned long long* g = keys + b * 16384 + w * 4096;
    int tid = threadIdx.x;
#pragma unroll
    for (int t = 0; t < 8; t++) s[tid + t * 512] = g[tid + t * 512];
    __syncthreads();

    if (kmode == 0) {
        for (unsigned k = 2; k <= 4096; k <<= 1) {
            for (unsigned j = k >> 1; j > 0; j >>= 1) {
#pragma unroll
                for (int t = 0; t < 4; t++) {
                    unsigned p = tid + t * 512;
                    unsigned i = ((p & ~(j - 1)) << 1) | (p & (j - 1));
                    unsigned l = i | j;
                    unsigned gi = (w << 12) + i;
                    bool up = ((gi & k) == 0);
                    unsigned long long a = s[i], c = s[l];
                    bool sw = up ? (c > a) : (a > c);
                    if (sw) { s[i] = c; s[l] = a; }
                }
                __syncthreads();
            }
        }
    } else {
        unsigned k = (unsigned)kmode;
        for (unsigned j = 2048; j > 0; j >>= 1) {
#pragma unroll
            for (int t = 0; t < 4; t++) {
                unsigned p = tid + t * 512;
                unsigned i = ((p & ~(j - 1)) << 1) | (p & (j - 1));
                unsigned l = i | j;
                unsigned gi = (w << 12) + i;
                bool up = ((gi & k) == 0);
                unsigned long long a = s[i], c = s[l];
                bool sw = up ? (c > a) : (a > c);
                if (sw) { s[i] = c; s[l] = a; }
            }
            __syncthreads();
        }
    }
#pragma unroll
    for (int t = 0; t < 8; t++) g[tid + t * 512] = s[tid + t * 512];
}

__global__ void k_sort_global(unsigned long long* __restrict__ keys, int kk, int jj)
{
    int t = blockIdx.x * 256 + threadIdx.x;
    if (t >= 2 * 8192) return;
    int b = t >> 13;
    unsigned p = t & 8191;
    unsigned j = (unsigned)jj, k = (unsigned)kk;
    unsigned i = ((p & ~(j - 1)) << 1) | (p & (j - 1));
    unsigned l = i | j;
    bool up = ((i & k) == 0);
    unsigned long long* g = keys + b * 16384;
    unsigned long long a = g[i], c = g[l];
    bool sw = up ? (c > a) : (a > c);
    if (sw) { g[i] = c; g[l] = a; }
}

__global__ void k_gather_top(const unsigned long long* __restrict__ keys,
                             const float* __restrict__ proposals, float* __restrict__ topBoxes)
{
    int t = blockIdx.x * 256 + threadIdx.x;
    if (t >= 2 * PRE) return;
    int b = t / PRE, pos = t - b * PRE;
    unsigned long long key = keys[b * 16384 + pos];
    unsigned idx = ~(unsigned)(key & 0xFFFFFFFFull);
    ((float4*)topBoxes)[t] = ((const float4*)proposals)[b * 9216 + idx];
}

__global__ __launch_bounds__(64) void k_iou(const float* __restrict__ topBoxes,
                                            unsigned* __restrict__ mask)
{
    int blk = blockIdx.x;
    int b = blk / PRE, i = blk - b * PRE;
    int lane = threadIdx.x;
    const float4* boxes = ((const float4*)topBoxes) + b * PRE;
    float4 bi = boxes[i];
    float area_a = (bi.z - bi.x) * (bi.w - bi.y);
    if (lane < 63) {
        unsigned wbits = 0u;
        for (int t = 0; t < 32; t++) {
            int j = lane * 32 + t;
            if (j < PRE && j > i) {
                float4 bj = boxes[j];
                float area_b = (bj.z - bj.x) * (bj.w - bj.y);
                float ltx = fmaxf(bi.x, bj.x), lty = fmaxf(bi.y, bj.y);
                float rbx = fminf(bi.z, bj.z), rby = fminf(bi.w, bj.w);
                float iw = fmaxf(rbx - ltx, 0.f), ih = fmaxf(rby - lty, 0.f);
                float inter = iw * ih;
                float iou = inter / (area_a + area_b - inter + 1e-9f);
                if (iou > 0.7f) wbits |= (1u << t);
            }
        }
        mask[(b * PRE + i) * 63 + lane] = wbits;
    }
}

__global__ __launch_bounds__(64) void k_compact(const unsigned* __restrict__ keep,
                                                const float* __restrict__ topBoxes,
                                                float* __restrict__ props, float* __restrict__ validf)
{
    int b = blockIdx.x;
    int lane = threadIdx.x;
    unsigned kw = (lane < 63) ? keep[b * 63 + lane] : 0u;
    int cnt = __popc(kw);
    int inc = cnt;
    for (int off = 1; off < 64; off <<= 1) {
        int v = __shfl_up(inc, off);
        if (lane >= off) inc += v;
    }
    int excl = inc - cnt;
    for (int t = 0; t < 32; t++) {
        if ((kw >> t) & 1u) {
            int rank = excl + __popc(kw & ((1u << t) - 1u));
            if (rank < TOPN) {
                int j = lane * 32 + t;
                ((float4*)props)[b * TOPN + rank] = ((const float4*)topBoxes)[b * PRE + j];
                validf[b * TOPN + rank] = 1.0f;
            }
        }
    }
}

// ============================================================================
// k_combhead: roico + combine + head fused. One block per ROI (2*TOPN).
// ============================================================================

__global__ __launch_bounds__(256) void k_combhead(
    const ushort_t* __restrict__ T, const float* __restrict__ props,
    const float* __restrict__ validf, const float* __restrict__ b1,
    const float* __restrict__ w2, const float* __restrict__ b2,
    const float* __restrict__ wc, const float* __restrict__ bcb,
    const float* __restrict__ wr, const float* __restrict__ brb,
    float* __restrict__ out)
{
    int g = blockIdx.x;               // b*TOPN + n
    int b = g / TOPN;
    int tid = threadIdx.x;
    __shared__ float rc[48];
    __shared__ float s1[256], s2v[256], rg[4];

    float vm = validf[g];
    if (vm != 0.f && tid < 14) {
        float4 box = ((const float4*)props)[g];
        const float scale = 1.f / 32.f;
        float x1 = box.x * scale, y1 = box.y * scale;
        float x2 = box.z * scale, y2 = box.w * scale;
        if (tid < 7) {
            int u = tid;
            float xs = x1 + (u + 0.5f) * (x2 - x1) / 7.f;
            xs = fminf(fmaxf(xs, 0.f), 31.f);
            float x0f = floorf(xs);
            rc[u] = x0f;
            rc[7 + u] = fminf(x0f + 1.f, 31.f);
            rc[14 + u] = xs - x0f;
        } else {
            int u = tid - 7;
            float ys = y1 + (u + 0.5f) * (y2 - y1) / 7.f;
            ys = fminf(fmaxf(ys, 0.f), 31.f);
            float y0f = floorf(ys);
            rc[21 + u] = y0f;
            rc[28 + u] = fminf(y0f + 1.f, 31.f);
            rc[35 + u] = ys - y0f;
        }
    }
    __syncthreads();

    float acc = 0.f;
    const ushort_t* Tb = T + (size_t)b * 12845056;
    if (vm != 0.f) {
#pragma unroll
        for (int py = 0; py < 7; py++) {
            int y0 = (int)rc[21 + py], y1 = (int)rc[28 + py];
            float wy = rc[35 + py];
#pragma unroll
            for (int px = 0; px < 7; px++) {
                int x0 = (int)rc[px], x1 = (int)rc[7 + px];
                float wx = rc[14 + px];
                int qo = (py * 7 + px) * 256 + tid;
                float f00 = __uint_as_float((unsigned)Tb[(size_t)(y0 * 32 + x0) * 12544 + qo] << 16);
                float f01 = __uint_as_float((unsigned)Tb[(size_t)(y0 * 32 + x1) * 12544 + qo] << 16);
                float f10 = __uint_as_float((unsigned)Tb[(size_t)(y1 * 32 + x0) * 12544 + qo] << 16);
                float f11 = __uint_as_float((unsigned)Tb[(size_t)(y1 * 32 + x1) * 12544 + qo] << 16);
                acc += f00 * (1.f - wy) * (1.f - wx) + f01 * (1.f - wy) * wx
                     + f10 * wy * (1.f - wx) + f11 * wy * wx;
            }
        }
    }
    s1[tid] = fmaxf(acc + b1[tid], 0.f);
    __syncthreads();

    float a2 = b2[tid];
    for (int j = 0; j < 256; j++) a2 = fmaf(s1[j], w2[j * 256 + tid], a2);
    s2v[tid] = fmaxf(a2, 0.f);
    __syncthreads();
    if (tid < 21) {
        float a = bcb[tid];
        for (int j = 0; j < 256; j++) a = fmaf(s2v[j], wc[j * 21 + tid], a);
        out[8000 + g * 21 + tid] = a * vm;
    } else if (tid >= 32 && tid < 36) {
        int r = tid - 32;
        float a = brb[r];
        for (int j = 0; j < 256; j++) a = fmaf(s2v[j], wr[j * 4 + r], a);
        rg[r] = a * vm;
    }
    __syncthreads();
    if (tid == 0) {
        float4 pb = ((const float4*)props)[g];
        float w = pb.z - pb.x, h = pb.w - pb.y;
        float cx = pb.x + 0.5f * w, cy = pb.y + 0.5f * h;
        float dw = fminf(fmaxf(rg[2], -4.f), 4.f), dh = fminf(fmaxf(rg[3], -4.f), 4.f);
        float ncx = cx + rg[0] * w, ncy = cy + rg[1] * h;
        float nw = w * expf(dw), nh = h * expf(dh);
        float x1 = fminf(fmaxf(ncx - 0.5f * nw, 0.f), 1023.f);
        float y1 = fminf(fmaxf(ncy - 0.5f * nh, 0.f), 1023.f);
        float x2 = fminf(fmaxf(ncx + 0.5f * nw, 0.f), 1023.f);
        float y2 = fminf(fmaxf(ncy + 0.5f * nh, 0.f), 1023.f);
        ((float4*)out)[g] = make_float4(x1 * vm, y1 * vm, x2 * vm, y2 * vm);
    }
}

// ============================================================================
// launcher
// ============================================================================

extern "C" void kernel_launch(void* const* d_in, const int* in_sizes, int n_in,
                              void* d_out, int out_size, void* d_ws, size_t ws_size,
                              hipStream_t stream)
{
    const float* x          = (const float*)d_in[0];
    const float* backbone_w = (const float*)d_in[1];
    const float* backbone_b = (const float*)d_in[2];
    const float* rpn_w      = (const float*)d_in[3];
    const float* rpn_b      = (const float*)d_in[4];
    const float* rpn_cls_w  = (const float*)d_in[5];
    const float* rpn_cls_b  = (const float*)d_in[6];
    const float* rpn_reg_w  = (const float*)d_in[7];
    const float* rpn_reg_b  = (const float*)d_in[8];
    const float* fc1_w      = (const float*)d_in[9];
    const float* fc1_b      = (const float*)d_in[10];
    const float* fc2_w      = (const float*)d_in[11];
    const float* fc2_b      = (const float*)d_in[12];
    const float* cls_w      = (const float*)d_in[13];
    const float* cls_b      = (const float*)d_in[14];
    const float* reg_w      = (const float*)d_in[15];
    const float* reg_b      = (const float*)d_in[16];
    float* out = (float*)d_out;

    char* base = (char*)d_ws;
    size_t off = 0;
    auto alloc = [&](size_t bytes) {
        void* p = base + off;
        off = (off + bytes + 255) & ~(size_t)255;
        return p;
    };
    float* fm        = (float*)alloc((size_t)2 * 2048 * 1024 * 4);
    float* Cp        = (float*)alloc((size_t)16 * 512 * 2048 * 4);
    float* hT        = (float*)alloc(2048u * 512 * 4);
    float* Racc      = (float*)alloc(512u * 2048 * 4);
    float* cls_raw   = (float*)alloc(2048u * 18 * 4);
    float* reg_raw   = (float*)alloc(2048u * 36 * 4);
    float* proposals = (float*)alloc(2u * 9216 * 4 * 4);
    float* scores    = (float*)alloc(2u * 9216 * 4);
    unsigned long long* keys = (unsigned long long*)alloc(2u * 16384 * 8);
    float* topBoxes  = (float*)alloc(2u * PRE * 4 * 4);
    unsigned* ioumask= (unsigned*)alloc(2u * PRE * 63 * 4);
    unsigned* keep   = (unsigned*)alloc(2u * 63 * 4);
    float* props     = (float*)alloc(2u * TOPN * 4 * 4);
    float* validf    = (float*)alloc(2u * TOPN * 4);
    char*  arena     = (char*)alloc(119537664);

    // phase 1: backbone frags (3-way)
    ushort_t* Wb0 = (ushort_t*)(arena);
    ushort_t* Wb1 = (ushort_t*)(arena + 12582912);
    ushort_t* Wb2 = (ushort_t*)(arena + 25165824);
    ushort_t* Xf0 = (ushort_t*)(arena + 37748736);
    ushort_t* Xf1 = (ushort_t*)(arena + 50331648);
    ushort_t* Xf2 = (ushort_t*)(arena + 62914560);
    // phase 2: rpn frags (per K-quarter)
    ushort_t* Wr0 = (ushort_t*)(arena);
    ushort_t* Wr1 = (ushort_t*)(arena + 4718592);
    ushort_t* Wr2 = (ushort_t*)(arena + 9437184);
    ushort_t* Rb0 = (ushort_t*)(arena + 14155776);
    ushort_t* Rb1 = (ushort_t*)(arena + 33030144);
    ushort_t* Rb2 = (ushort_t*)(arena + 51904512);
    // phase 3: fc1 frags (plain bf16) + bf16 T
    ushort_t* Aq   = (ushort_t*)(arena);                  // 8.4 MB
    ushort_t* Tbuf = (ushort_t*)(arena + 16777216);       // 51.4 MB
    ushort_t* Bq   = (ushort_t*)Cp;                       // 51.4 MB alias

    k_convW3<<<3072, 256, 0, stream>>>(backbone_w, Wb0, Wb1, Wb2, 3072, 0, 96);
    k_convX3<<<3072, 256, 0, stream>>>(x, Xf0, Xf1, Xf2);
    k_gemm6<<<dim3(16, 16, 3), 256, 0, stream>>>(Wb0, Wb1, Wb2, Xf0, Xf1, Xf2,
                                                 Cp, 32, 96, 2048);
    k_backbone_reduce<<<(2048 * 2048) / 256, 256, 0, stream>>>(Cp, backbone_b, fm);

    for (int q = 0; q < 4; q++) {
        k_convW3<<<1152, 256, 0, stream>>>(rpn_w, Wr0, Wr1, Wr2, 18432, q * 4608, 144);
        k_convR3<<<4608, 256, 0, stream>>>(fm, Rb0, Rb1, Rb2, q * 4608, 144);
        k_gemm6<<<dim3(4, 16, 8), 256, 0, stream>>>(Wr0, Wr1, Wr2, Rb0, Rb1, Rb2,
                                                    Cp, 18, 144, 2048);
        k_rpn_acc<<<4096, 256, 0, stream>>>(Cp, Racc, q == 0 ? 1 : 0);
    }
    k_rpn_final<<<4096, 256, 0, stream>>>(Racc, rpn_b, hT);

    k_convB<<<12544, 256, 0, stream>>>(fc1_w, Bq);
    k_convA<<<2048, 256, 0, stream>>>(fm, Aq);

    k_clsreg<<<2048, 64, 0, stream>>>(hT, rpn_cls_w, rpn_cls_b, rpn_reg_w, rpn_reg_b,
                                      cls_raw, reg_raw);
    k_proposals<<<(2 * 9216 + 255) / 256, 256, 0, stream>>>(cls_raw, reg_raw, proposals, scores);

    k_sort_init<<<(2 * 16384) / 256, 256, 0, stream>>>(scores, keys);
    k_sort_lds<<<8, 512, 0, stream>>>(keys, 0, 4);
    k_sort_global<<<64, 256, 0, stream>>>(keys, 8192, 4096);
    k_sort_lds<<<8, 512, 0, stream>>>(keys, 8192, 4);
    k_sort_global<<<64, 256, 0, stream>>>(keys, 16384, 8192);
    k_sort_global<<<64, 256, 0, stream>>>(keys, 16384, 4096);
    k_sort_lds<<<2, 512, 0, stream>>>(keys, 16384, 1);
    k_gather_top<<<(2 * PRE + 255) / 256, 256, 0, stream>>>(keys, proposals, topBoxes);

    k_iou<<<2 * PRE, 64, 0, stream>>>(topBoxes, ioumask);
    hipMemsetAsync(props, 0, 2u * TOPN * 4 * 4, stream);
    hipMemsetAsync(validf, 0, 2u * TOPN * 4, stream);

    // fused: greedy NMS (blocks 0-1, start first) + fc1 GEMM (blocks 2-1569)
    k_fused<<<1570, 256, 0, stream>>>(Aq, Bq, Tbuf, ioumask, keep);

    k_compact<<<2, 64, 0, stream>>>(keep, topBoxes, props, validf);
    k_combhead<<<2 * TOPN, 256, 0, stream>>>(Tbuf, props, validf, fc1_b,
                                             fc2_w, fc2_b, cls_w, cls_b, reg_w, reg_b,
                                             out);
}